// Round 3
// baseline (1126.149 us; speedup 1.0000x reference)
//
#include <hip/hip_runtime.h>

typedef unsigned short u16;

#define F 128
#define F3 384
#define TA 32          // atoms per MLP block
#define PAD 36         // padded LDS row (floats)

__device__ __forceinline__ float bf2f(u16 v) {
    union { unsigned int u; float f; } c; c.u = ((unsigned int)v) << 16; return c.f;
}
__device__ __forceinline__ u16 f2bf(float f) {
    union { float fv; unsigned int u; } c; c.fv = f;
    unsigned int u = c.u;
    return (u16)((u + 0x7fffu + ((u >> 16) & 1u)) >> 16);   // round-nearest-even
}

// dtype-generic load/store: BF=true -> bf16 (u16) arrays, else f32 arrays
template<bool BF> __device__ __forceinline__ float LD(const void* p, size_t i) {
    return BF ? bf2f(((const u16*)p)[i]) : ((const float*)p)[i];
}
template<bool BF> __device__ __forceinline__ void ST(void* p, size_t i, float v) {
    if (BF) ((u16*)p)[i] = f2bf(v); else ((float*)p)[i] = v;
}

// ---------------------------------------------------------------------------
// Dtype detector: even-indexed u16s of a bf16 array are real bf16 values
// (exponent field ~always in [100,150] for N(0,1) data); for an f32 array the
// even u16 is low mantissa bits -> exponent field uniform (~20% in range).
// ---------------------------------------------------------------------------
__global__ __launch_bounds__(256) void detect_kernel(const void* q, int* flag) {
    __shared__ int cnt;
    if (threadIdx.x == 0) cnt = 0;
    __syncthreads();
    const u16* p = (const u16*)q;
    int c = 0;
    for (int i = threadIdx.x; i < 1024; i += 256) {
        u16 v = p[2 * i];
        int e = (v >> 7) & 0xFF;
        if (e >= 100 && e <= 150) c++;
    }
    atomicAdd(&cnt, c);
    __syncthreads();
    if (threadIdx.x == 0) *flag = (cnt > 512) ? 1 : 0;
}

// ---------------------------------------------------------------------------
// MLP, one 128-col output chunk per call:
//   h = silu(q@W1+b1);  xc = (h @ W2[:, cb*128:(cb+1)*128] + b2[chunk])  -> bf16
// ---------------------------------------------------------------------------
template<bool BF>
__device__ void mlp_body(const void* q, const void* W1, const void* b1,
                         const void* W2, const void* b2,
                         u16* __restrict__ xc, int cb, int n_atoms)
{
    __shared__ float qT[F][PAD];  // [feature][atom]
    __shared__ float hT[F][PAD];

    const int tid = threadIdx.x;
    const int a0  = blockIdx.x * TA;

    for (int i = tid; i < TA * F; i += 256) {
        int a = i >> 7, f = i & 127;
        qT[f][a] = (a0 + a < n_atoms) ? LD<BF>(q, (size_t)(a0 + a) * F + f) : 0.0f;
    }
    __syncthreads();

    const int c4 = (tid & 31) * 4;
    const int r4 = (tid >> 5) * 4;

    // phase 1: h = silu(q@W1 + b1)
    float acc[4][4];
#pragma unroll
    for (int rr = 0; rr < 4; ++rr)
#pragma unroll
        for (int cc = 0; cc < 4; ++cc) acc[rr][cc] = 0.0f;

    for (int f = 0; f < F; ++f) {
        float4 qv = *(const float4*)&qT[f][r4];
        float qa[4] = {qv.x, qv.y, qv.z, qv.w};
        float w[4];
#pragma unroll
        for (int cc = 0; cc < 4; ++cc) w[cc] = LD<BF>(W1, (size_t)f * F + c4 + cc);
#pragma unroll
        for (int rr = 0; rr < 4; ++rr)
#pragma unroll
            for (int cc = 0; cc < 4; ++cc)
                acc[rr][cc] += qa[rr] * w[cc];
    }
#pragma unroll
    for (int cc = 0; cc < 4; ++cc) {
        float bb = LD<BF>(b1, c4 + cc);
#pragma unroll
        for (int rr = 0; rr < 4; ++rr) {
            float h = acc[rr][cc] + bb;
            hT[c4 + cc][r4 + rr] = h / (1.0f + __expf(-h));
        }
    }
    __syncthreads();

    // phase 2: chunk cb of x
#pragma unroll
    for (int rr = 0; rr < 4; ++rr)
#pragma unroll
        for (int cc = 0; cc < 4; ++cc) acc[rr][cc] = 0.0f;

    for (int f = 0; f < F; ++f) {
        float4 hv = *(const float4*)&hT[f][r4];
        float ha[4] = {hv.x, hv.y, hv.z, hv.w};
        float w[4];
#pragma unroll
        for (int cc = 0; cc < 4; ++cc)
            w[cc] = LD<BF>(W2, (size_t)f * F3 + cb * F + c4 + cc);
#pragma unroll
        for (int rr = 0; rr < 4; ++rr)
#pragma unroll
            for (int cc = 0; cc < 4; ++cc)
                acc[rr][cc] += ha[rr] * w[cc];
    }
#pragma unroll
    for (int cc = 0; cc < 4; ++cc) {
        float bb = LD<BF>(b2, cb * F + c4 + cc);
#pragma unroll
        for (int rr = 0; rr < 4; ++rr) {
            int ga = a0 + r4 + rr;
            if (ga < n_atoms)
                xc[(size_t)ga * F + c4 + cc] = f2bf(acc[rr][cc] + bb);
        }
    }
}

__global__ __launch_bounds__(256) void mlp_kernel(
    const void* q, const void* W1, const void* b1, const void* W2, const void* b2,
    u16* xc, int cb, int n_atoms, const int* flag)
{
    if (*flag) mlp_body<true >(q, W1, b1, W2, b2, xc, cb, n_atoms);
    else       mlp_body<false>(q, W1, b1, W2, b2, xc, cb, n_atoms);
}

// ---------------------------------------------------------------------------
// CSR build: count -> scan -> scatter perm
// ---------------------------------------------------------------------------
__global__ __launch_bounds__(256) void count_kernel(
    const int* __restrict__ idx_i, int* __restrict__ counts, int E)
{
    int e = blockIdx.x * 256 + threadIdx.x;
    if (e < E) atomicAdd(&counts[idx_i[e]], 1);
}

__global__ __launch_bounds__(1024) void scan_kernel(
    const int* __restrict__ counts, int* __restrict__ offsets, int n)
{
    __shared__ int buf[1024];
    __shared__ int carryS;
    const int t = threadIdx.x;
    if (t == 0) carryS = 0;
    __syncthreads();

    for (int base = 0; base < n; base += 8192) {
        int idx0 = base + t * 8;
        int c[8];
#pragma unroll
        for (int r = 0; r < 8; ++r) c[r] = (idx0 + r < n) ? counts[idx0 + r] : 0;
        int s = 0;
#pragma unroll
        for (int r = 0; r < 8; ++r) s += c[r];
        buf[t] = s;
        __syncthreads();
        for (int off = 1; off < 1024; off <<= 1) {
            int add = (t >= off) ? buf[t - off] : 0;
            __syncthreads();
            buf[t] += add;
            __syncthreads();
        }
        int run = carryS + buf[t] - s;
#pragma unroll
        for (int r = 0; r < 8; ++r) {
            if (idx0 + r < n) offsets[idx0 + r] = run;
            run += c[r];
        }
        __syncthreads();
        if (t == 0) carryS += buf[1023];
        __syncthreads();
    }
    if (t == 0) offsets[n] = carryS;
}

__global__ __launch_bounds__(256) void scatter_kernel(
    const int* __restrict__ idx_i, const int* __restrict__ offsets,
    int* __restrict__ cursor, int* __restrict__ perm, int E)
{
    int e = blockIdx.x * 256 + threadIdx.x;
    if (e < E) {
        int i = idx_i[e];
        int pos = offsets[i] + atomicAdd(&cursor[i], 1);
        perm[pos] = e;
    }
}

// ---------------------------------------------------------------------------
// Gather pass 0: out_q[a] = q[a] + sum_e Wq[e]*xq[j]
// ---------------------------------------------------------------------------
template<bool BF>
__device__ void gq_body(const void* q, const void* Wij, const u16* __restrict__ xc,
                        const int* __restrict__ idx_j, const int* __restrict__ offsets,
                        const int* __restrict__ perm, void* out, int n_atoms, int E)
{
    int a = blockIdx.x * 2 + (threadIdx.x >> 7);
    int f = threadIdx.x & 127;
    if (a >= n_atoms) return;

    float s = LD<BF>(q, (size_t)a * F + f);
    int k0 = offsets[a], k1 = offsets[a + 1];
    for (int k = k0; k < k1; ++k) {
        int e = perm[k];  if ((unsigned)e >= (unsigned)E) e = 0;
        int j = idx_j[e]; if ((unsigned)j >= (unsigned)n_atoms) j = 0;
        s += LD<BF>(Wij, (size_t)e * F3 + f) * bf2f(xc[(size_t)j * F + f]);
    }
    ST<BF>(out, (size_t)a * F + f, s);
}

__global__ __launch_bounds__(256) void gather_q_kernel(
    const void* q, const void* Wij, const u16* xc, const int* idx_j,
    const int* offsets, const int* perm, void* out, int n_atoms, int E, const int* flag)
{
    if (*flag) gq_body<true >(q, Wij, xc, idx_j, offsets, perm, out, n_atoms, E);
    else       gq_body<false>(q, Wij, xc, idx_j, offsets, perm, out, n_atoms, E);
}

// ---------------------------------------------------------------------------
// Gather passes 1/2 on mu output:
//   mode 1: out_mu = mu_a + sum_e (WR[e]*xR[j]) * dir[e]      (first write)
//   mode 2: out_mu += sum_e (Wm[e]*xm[j]) * mu_j              (accumulate)
// ---------------------------------------------------------------------------
template<bool BF>
__device__ void gmu_body(const void* mu, const void* Wij, const void* dir,
                         const u16* __restrict__ xc, const int* __restrict__ idx_j,
                         const int* __restrict__ offsets, const int* __restrict__ perm,
                         void* out, int n_atoms, int E, int mode)
{
    int a = blockIdx.x * 2 + (threadIdx.x >> 7);
    int f = threadIdx.x & 127;
    if (a >= n_atoms) return;

    const size_t ob = (size_t)n_atoms * F;   // mu section start in out
    float s0, s1, s2;
    if (mode == 1) {
        s0 = LD<BF>(mu, (size_t)a * F3 + f);
        s1 = LD<BF>(mu, (size_t)a * F3 + 128 + f);
        s2 = LD<BF>(mu, (size_t)a * F3 + 256 + f);
    } else {
        s0 = LD<BF>(out, ob + (size_t)a * F3 + f);
        s1 = LD<BF>(out, ob + (size_t)a * F3 + 128 + f);
        s2 = LD<BF>(out, ob + (size_t)a * F3 + 256 + f);
    }

    const int wofs = (mode == 1) ? 128 : 256;
    int k0 = offsets[a], k1 = offsets[a + 1];
    for (int k = k0; k < k1; ++k) {
        int e = perm[k];  if ((unsigned)e >= (unsigned)E) e = 0;
        int j = idx_j[e]; if ((unsigned)j >= (unsigned)n_atoms) j = 0;
        float wx = LD<BF>(Wij, (size_t)e * F3 + wofs + f) * bf2f(xc[(size_t)j * F + f]);
        if (mode == 1) {
            s0 += wx * LD<BF>(dir, (size_t)e * 3 + 0);
            s1 += wx * LD<BF>(dir, (size_t)e * 3 + 1);
            s2 += wx * LD<BF>(dir, (size_t)e * 3 + 2);
        } else {
            s0 += wx * LD<BF>(mu, (size_t)j * F3 + f);
            s1 += wx * LD<BF>(mu, (size_t)j * F3 + 128 + f);
            s2 += wx * LD<BF>(mu, (size_t)j * F3 + 256 + f);
        }
    }
    ST<BF>(out, ob + (size_t)a * F3 + f,       s0);
    ST<BF>(out, ob + (size_t)a * F3 + 128 + f, s1);
    ST<BF>(out, ob + (size_t)a * F3 + 256 + f, s2);
}

__global__ __launch_bounds__(256) void gather_mu_kernel(
    const void* mu, const void* Wij, const void* dir, const u16* xc,
    const int* idx_j, const int* offsets, const int* perm, void* out,
    int n_atoms, int E, int mode, const int* flag)
{
    if (*flag) gmu_body<true >(mu, Wij, dir, xc, idx_j, offsets, perm, out, n_atoms, E, mode);
    else       gmu_body<false>(mu, Wij, dir, xc, idx_j, offsets, perm, out, n_atoms, E, mode);
}

// ---------------------------------------------------------------------------
extern "C" void kernel_launch(void* const* d_in, const int* in_sizes, int n_in,
                              void* d_out, int out_size, void* d_ws, size_t ws_size,
                              hipStream_t stream)
{
    const void* q   = d_in[0];
    const void* mu  = d_in[1];
    const void* Wij = d_in[2];
    const void* dir = d_in[3];
    const void* W1  = d_in[4];
    const void* b1  = d_in[5];
    const void* W2  = d_in[6];
    const void* b2  = d_in[7];
    const int* idx_i = (const int*)d_in[8];
    const int* idx_j = (const int*)d_in[9];

    const int n_atoms = in_sizes[0] / F;        // 50000
    const int E       = in_sizes[8];            // 500000

    // ws layout (~15.4 MB):
    //   xc bf16 [A*128] | flag int[4] | counts int[A] | cursor int[A]
    //   | offsets int[A+1] | perm int[E]
    u16* xc      = (u16*)d_ws;
    int* flag    = (int*)(xc + (size_t)n_atoms * F);
    int* counts  = flag + 4;
    int* cursor  = counts + n_atoms;
    int* offsets = cursor + n_atoms;
    int* perm    = offsets + n_atoms + 1;

    detect_kernel<<<1, 256, 0, stream>>>(q, flag);

    hipMemsetAsync(counts, 0, (size_t)2 * n_atoms * sizeof(int), stream);
    int eBlocks = (E + 255) / 256;
    count_kernel<<<eBlocks, 256, 0, stream>>>(idx_i, counts, E);
    scan_kernel<<<1, 1024, 0, stream>>>(counts, offsets, n_atoms);
    scatter_kernel<<<eBlocks, 256, 0, stream>>>(idx_i, offsets, cursor, perm, E);

    int mlpBlocks = (n_atoms + TA - 1) / TA;
    int gBlocks   = (n_atoms + 1) / 2;

    // pass 0: xq -> out_q
    mlp_kernel<<<mlpBlocks, 256, 0, stream>>>(q, W1, b1, W2, b2, xc, 0, n_atoms, flag);
    gather_q_kernel<<<gBlocks, 256, 0, stream>>>(q, Wij, xc, idx_j, offsets, perm,
                                                 d_out, n_atoms, E, flag);
    // pass 1: xR -> out_mu = mu + dmuR*dir
    mlp_kernel<<<mlpBlocks, 256, 0, stream>>>(q, W1, b1, W2, b2, xc, 1, n_atoms, flag);
    gather_mu_kernel<<<gBlocks, 256, 0, stream>>>(mu, Wij, dir, xc, idx_j, offsets, perm,
                                                  d_out, n_atoms, E, 1, flag);
    // pass 2: xm -> out_mu += dmumu*mu_j
    mlp_kernel<<<mlpBlocks, 256, 0, stream>>>(q, W1, b1, W2, b2, xc, 2, n_atoms, flag);
    gather_mu_kernel<<<gBlocks, 256, 0, stream>>>(mu, Wij, dir, xc, idx_j, offsets, perm,
                                                  d_out, n_atoms, E, 2, flag);
}

// Round 4
// 682.041 us; speedup vs baseline: 1.6511x; 1.6511x over previous
//
#include <hip/hip_runtime.h>

typedef unsigned short u16;
typedef unsigned int   u32;

#define F 128
#define F3 384
#define TA 32          // atoms per MLP block
#define PAD 36         // padded LDS row (floats)

__device__ __forceinline__ float bf2f(u16 v) {
    union { u32 u; float f; } c; c.u = ((u32)v) << 16; return c.f;
}
__device__ __forceinline__ u16 f2bf(float f) {
    union { float fv; u32 u; } c; c.fv = f;
    u32 u = c.u;
    return (u16)((u + 0x7fffu + ((u >> 16) & 1u)) >> 16);   // round-nearest-even
}

// dtype-generic accessors: BF=true -> bf16 (u16) arrays, false -> f32 arrays
template<bool BF> __device__ __forceinline__ float LD(const void* p, size_t i) {
    return BF ? bf2f(((const u16*)p)[i]) : ((const float*)p)[i];
}
template<bool BF> __device__ __forceinline__ void ST(void* p, size_t i, float v) {
    if (BF) ((u16*)p)[i] = f2bf(v); else ((float*)p)[i] = v;
}
template<bool BF> __device__ __forceinline__ float2 LD2(const void* p, size_t i) {
    if (BF) {
        u32 v = *(const u32*)((const u16*)p + i);
        float2 r; r.x = bf2f((u16)(v & 0xffff)); r.y = bf2f((u16)(v >> 16)); return r;
    }
    return *(const float2*)((const float*)p + i);
}
template<bool BF> __device__ __forceinline__ void ST2(void* p, size_t i, float2 v) {
    if (BF) { *(u32*)((u16*)p + i) = ((u32)f2bf(v.y) << 16) | f2bf(v.x); }
    else    { *(float2*)((float*)p + i) = v; }
}
__device__ __forceinline__ float2 LD2bf(const u16* p, size_t i) {
    u32 v = *(const u32*)(p + i);
    float2 r; r.x = bf2f((u16)(v & 0xffff)); r.y = bf2f((u16)(v >> 16)); return r;
}
template<bool BF> __device__ __forceinline__ float4 LD4(const void* p, size_t i) {
    if (BF) {
        uint2 v = *(const uint2*)((const u16*)p + i);
        float4 r;
        r.x = bf2f((u16)(v.x & 0xffff)); r.y = bf2f((u16)(v.x >> 16));
        r.z = bf2f((u16)(v.y & 0xffff)); r.w = bf2f((u16)(v.y >> 16));
        return r;
    }
    return *(const float4*)((const float*)p + i);
}

// ---------------------------------------------------------------------------
// Dtype detector (kept from round 3 — proven): bf16 arrays have sane exponents
// at even u16 indices; f32 arrays don't.
// ---------------------------------------------------------------------------
__global__ __launch_bounds__(256) void detect_kernel(const void* q, int* flag) {
    __shared__ int cnt;
    if (threadIdx.x == 0) cnt = 0;
    __syncthreads();
    const u16* p = (const u16*)q;
    int c = 0;
    for (int i = threadIdx.x; i < 1024; i += 256) {
        u16 v = p[2 * i];
        int e = (v >> 7) & 0xFF;
        if (e >= 100 && e <= 150) c++;
    }
    atomicAdd(&cnt, c);
    __syncthreads();
    if (threadIdx.x == 0) *flag = (cnt > 512) ? 1 : 0;
}

// ---------------------------------------------------------------------------
// MLP. mode 0: recompute h from q, emit chunk cb.
//      mode 1: compute h from q, STORE h to hbuf, emit chunk cb.
//      mode 2: load h from hbuf, emit chunk cb.
// ---------------------------------------------------------------------------
template<bool BF>
__device__ void mlp_body(const void* q, const void* W1, const void* b1,
                         const void* W2, const void* b2,
                         u16* __restrict__ xc, u16* __restrict__ hbuf,
                         int cb, int mode, int n_atoms)
{
    __shared__ float qT[F][PAD];  // [feature][atom]
    __shared__ float hT[F][PAD];

    const int tid = threadIdx.x;
    const int a0  = blockIdx.x * TA;
    const int c4  = (tid & 31) * 4;
    const int r4  = (tid >> 5) * 4;

    if (mode == 2) {
        // stage h (bf16) -> hT
        for (int i = tid; i < TA * F / 8; i += 256) {
            int a = i >> 4, f0 = (i & 15) * 8;
            float4 v0, v1;
            if (a0 + a < n_atoms) {
                v0 = LD4<true>(hbuf, (size_t)(a0 + a) * F + f0);
                v1 = LD4<true>(hbuf, (size_t)(a0 + a) * F + f0 + 4);
            } else { v0 = v1 = make_float4(0, 0, 0, 0); }
            hT[f0 + 0][a] = v0.x; hT[f0 + 1][a] = v0.y; hT[f0 + 2][a] = v0.z; hT[f0 + 3][a] = v0.w;
            hT[f0 + 4][a] = v1.x; hT[f0 + 5][a] = v1.y; hT[f0 + 6][a] = v1.z; hT[f0 + 7][a] = v1.w;
        }
        __syncthreads();
    } else {
        // stage q -> qT
        for (int i = tid; i < TA * F / 8; i += 256) {
            int a = i >> 4, f0 = (i & 15) * 8;
            float4 v0, v1;
            if (a0 + a < n_atoms) {
                v0 = LD4<BF>(q, (size_t)(a0 + a) * F + f0);
                v1 = LD4<BF>(q, (size_t)(a0 + a) * F + f0 + 4);
            } else { v0 = v1 = make_float4(0, 0, 0, 0); }
            qT[f0 + 0][a] = v0.x; qT[f0 + 1][a] = v0.y; qT[f0 + 2][a] = v0.z; qT[f0 + 3][a] = v0.w;
            qT[f0 + 4][a] = v1.x; qT[f0 + 5][a] = v1.y; qT[f0 + 6][a] = v1.z; qT[f0 + 7][a] = v1.w;
        }
        __syncthreads();

        // phase 1: h = silu(q@W1 + b1)
        float acc[4][4];
#pragma unroll
        for (int rr = 0; rr < 4; ++rr)
#pragma unroll
            for (int cc = 0; cc < 4; ++cc) acc[rr][cc] = 0.0f;

        for (int f = 0; f < F; ++f) {
            float4 qv = *(const float4*)&qT[f][r4];
            float4 w  = LD4<BF>(W1, (size_t)f * F + c4);
            float qa[4] = {qv.x, qv.y, qv.z, qv.w};
            float wa[4] = {w.x, w.y, w.z, w.w};
#pragma unroll
            for (int rr = 0; rr < 4; ++rr)
#pragma unroll
                for (int cc = 0; cc < 4; ++cc)
                    acc[rr][cc] += qa[rr] * wa[cc];
        }
        float hv[4][4];
#pragma unroll
        for (int cc = 0; cc < 4; ++cc) {
            float bb = LD<BF>(b1, c4 + cc);
#pragma unroll
            for (int rr = 0; rr < 4; ++rr) {
                float h = acc[rr][cc] + bb;
                float s = h / (1.0f + __expf(-h));
                hv[rr][cc] = s;
                hT[c4 + cc][r4 + rr] = s;
            }
        }
        if (mode == 1) {
#pragma unroll
            for (int rr = 0; rr < 4; ++rr) {
                int ga = a0 + r4 + rr;
                if (ga < n_atoms) {
                    *(u32*)(hbuf + (size_t)ga * F + c4)     = ((u32)f2bf(hv[rr][1]) << 16) | f2bf(hv[rr][0]);
                    *(u32*)(hbuf + (size_t)ga * F + c4 + 2) = ((u32)f2bf(hv[rr][3]) << 16) | f2bf(hv[rr][2]);
                }
            }
        }
        __syncthreads();
    }

    // phase 2: xc = h @ W2[:, cb*128 : cb*128+128] + b2[chunk]
    float acc[4][4];
#pragma unroll
    for (int rr = 0; rr < 4; ++rr)
#pragma unroll
        for (int cc = 0; cc < 4; ++cc) acc[rr][cc] = 0.0f;

    for (int f = 0; f < F; ++f) {
        float4 hv = *(const float4*)&hT[f][r4];
        float4 w  = LD4<BF>(W2, (size_t)f * F3 + cb * F + c4);
        float ha[4] = {hv.x, hv.y, hv.z, hv.w};
        float wa[4] = {w.x, w.y, w.z, w.w};
#pragma unroll
        for (int rr = 0; rr < 4; ++rr)
#pragma unroll
            for (int cc = 0; cc < 4; ++cc)
                acc[rr][cc] += ha[rr] * wa[cc];
    }
    float bb[4];
#pragma unroll
    for (int cc = 0; cc < 4; ++cc) bb[cc] = LD<BF>(b2, cb * F + c4 + cc);
#pragma unroll
    for (int rr = 0; rr < 4; ++rr) {
        int ga = a0 + r4 + rr;
        if (ga < n_atoms) {
            float x0 = acc[rr][0] + bb[0], x1 = acc[rr][1] + bb[1];
            float x2 = acc[rr][2] + bb[2], x3 = acc[rr][3] + bb[3];
            *(u32*)(xc + (size_t)ga * F + c4)     = ((u32)f2bf(x1) << 16) | f2bf(x0);
            *(u32*)(xc + (size_t)ga * F + c4 + 2) = ((u32)f2bf(x3) << 16) | f2bf(x2);
        }
    }
}

__global__ __launch_bounds__(256) void mlp_kernel(
    const void* q, const void* W1, const void* b1, const void* W2, const void* b2,
    u16* xc, u16* hbuf, int cb, int mode, int n_atoms, const int* flag)
{
    if (*flag) mlp_body<true >(q, W1, b1, W2, b2, xc, hbuf, cb, mode, n_atoms);
    else       mlp_body<false>(q, W1, b1, W2, b2, xc, hbuf, cb, mode, n_atoms);
}

// ---------------------------------------------------------------------------
// CSR build: count -> scan -> scatter perm   (unchanged, known-good)
// ---------------------------------------------------------------------------
__global__ __launch_bounds__(256) void count_kernel(
    const int* __restrict__ idx_i, int* __restrict__ counts, int E)
{
    int e = blockIdx.x * 256 + threadIdx.x;
    if (e < E) atomicAdd(&counts[idx_i[e]], 1);
}

__global__ __launch_bounds__(1024) void scan_kernel(
    const int* __restrict__ counts, int* __restrict__ offsets, int n)
{
    __shared__ int buf[1024];
    __shared__ int carryS;
    const int t = threadIdx.x;
    if (t == 0) carryS = 0;
    __syncthreads();

    for (int base = 0; base < n; base += 8192) {
        int idx0 = base + t * 8;
        int c[8];
#pragma unroll
        for (int r = 0; r < 8; ++r) c[r] = (idx0 + r < n) ? counts[idx0 + r] : 0;
        int s = 0;
#pragma unroll
        for (int r = 0; r < 8; ++r) s += c[r];
        buf[t] = s;
        __syncthreads();
        for (int off = 1; off < 1024; off <<= 1) {
            int add = (t >= off) ? buf[t - off] : 0;
            __syncthreads();
            buf[t] += add;
            __syncthreads();
        }
        int run = carryS + buf[t] - s;
#pragma unroll
        for (int r = 0; r < 8; ++r) {
            if (idx0 + r < n) offsets[idx0 + r] = run;
            run += c[r];
        }
        __syncthreads();
        if (t == 0) carryS += buf[1023];
        __syncthreads();
    }
    if (t == 0) offsets[n] = carryS;
}

__global__ __launch_bounds__(256) void scatter_kernel(
    const int* __restrict__ idx_i, const int* __restrict__ offsets,
    int* __restrict__ cursor, int* __restrict__ perm, int E)
{
    int e = blockIdx.x * 256 + threadIdx.x;
    if (e < E) {
        int i = idx_i[e];
        int pos = offsets[i] + atomicAdd(&cursor[i], 1);
        perm[pos] = e;
    }
}

// ---------------------------------------------------------------------------
// Gather pass 0: out_q[a] = q[a] + sum_e Wq[e]*xq[j]
// 1 wave = 1 atom; lane owns features {2l, 2l+1}; edge (e,j) batch-staged in
// registers (lane-per-edge) and broadcast via __shfl — no per-edge pointer chase.
// ---------------------------------------------------------------------------
template<bool BF>
__device__ void gq_body(const void* q, const void* Wij, const u16* __restrict__ xc,
                        const int* __restrict__ idx_j, const int* __restrict__ offsets,
                        const int* __restrict__ perm, void* out, int n_atoms, int E)
{
    int a    = blockIdx.x * 4 + (threadIdx.x >> 6);
    int lane = threadIdx.x & 63;
    if (a >= n_atoms) return;
    const size_t fo = 2 * lane;

    float2 s = LD2<BF>(q, (size_t)a * F + fo);
    int k0 = offsets[a], k1 = offsets[a + 1];
    for (int kb = k0; kb < k1; kb += 64) {
        int cnt = k1 - kb; if (cnt > 64) cnt = 64;
        int e_r = 0, j_r = 0;
        if (lane < cnt) {
            e_r = perm[kb + lane]; if ((unsigned)e_r >= (unsigned)E) e_r = 0;
            j_r = idx_j[e_r];      if ((unsigned)j_r >= (unsigned)n_atoms) j_r = 0;
        }
        for (int c = 0; c < cnt; ++c) {
            int e = __shfl(e_r, c, 64);
            int j = __shfl(j_r, c, 64);
            float2 w  = LD2<BF>(Wij, (size_t)e * F3 + fo);
            float2 xv = LD2bf(xc, (size_t)j * F + fo);
            s.x += w.x * xv.x;
            s.y += w.y * xv.y;
        }
    }
    ST2<BF>(out, (size_t)a * F + fo, s);
}

__global__ __launch_bounds__(256) void gather_q_kernel(
    const void* q, const void* Wij, const u16* xc, const int* idx_j,
    const int* offsets, const int* perm, void* out, int n_atoms, int E, const int* flag)
{
    if (*flag) gq_body<true >(q, Wij, xc, idx_j, offsets, perm, out, n_atoms, E);
    else       gq_body<false>(q, Wij, xc, idx_j, offsets, perm, out, n_atoms, E);
}

// ---------------------------------------------------------------------------
// Gather mu passes:
//   MODE 1: out_mu = mu_a + sum_e (WR[e]*xR[j]) * dir[e]   (first write)
//   MODE 2: out_mu += sum_e (Wm[e]*xm[j]) * mu_j           (accumulate)
// ---------------------------------------------------------------------------
template<bool BF, int MODE>
__device__ void gmu_body(const void* mu, const void* Wij, const void* dir,
                         const u16* __restrict__ xc, const int* __restrict__ idx_j,
                         const int* __restrict__ offsets, const int* __restrict__ perm,
                         void* out, int n_atoms, int E)
{
    int a    = blockIdx.x * 4 + (threadIdx.x >> 6);
    int lane = threadIdx.x & 63;
    if (a >= n_atoms) return;
    const size_t fo = 2 * lane;
    const size_t ob = (size_t)n_atoms * F;

    float2 s0, s1, s2;
    if (MODE == 1) {
        s0 = LD2<BF>(mu, (size_t)a * F3 + fo);
        s1 = LD2<BF>(mu, (size_t)a * F3 + 128 + fo);
        s2 = LD2<BF>(mu, (size_t)a * F3 + 256 + fo);
    } else {
        s0 = LD2<BF>(out, ob + (size_t)a * F3 + fo);
        s1 = LD2<BF>(out, ob + (size_t)a * F3 + 128 + fo);
        s2 = LD2<BF>(out, ob + (size_t)a * F3 + 256 + fo);
    }

    const int wofs = (MODE == 1) ? 128 : 256;
    int k0 = offsets[a], k1 = offsets[a + 1];
    for (int kb = k0; kb < k1; kb += 64) {
        int cnt = k1 - kb; if (cnt > 64) cnt = 64;
        int e_r = 0, j_r = 0;
        if (lane < cnt) {
            e_r = perm[kb + lane]; if ((unsigned)e_r >= (unsigned)E) e_r = 0;
            j_r = idx_j[e_r];      if ((unsigned)j_r >= (unsigned)n_atoms) j_r = 0;
        }
        for (int c = 0; c < cnt; ++c) {
            int e = __shfl(e_r, c, 64);
            int j = __shfl(j_r, c, 64);
            float2 w  = LD2<BF>(Wij, (size_t)e * F3 + wofs + fo);
            float2 xv = LD2bf(xc, (size_t)j * F + fo);
            float wx0 = w.x * xv.x, wx1 = w.y * xv.y;
            if (MODE == 1) {
                float d0 = LD<BF>(dir, (size_t)e * 3 + 0);
                float d1 = LD<BF>(dir, (size_t)e * 3 + 1);
                float d2 = LD<BF>(dir, (size_t)e * 3 + 2);
                s0.x += wx0 * d0; s0.y += wx1 * d0;
                s1.x += wx0 * d1; s1.y += wx1 * d1;
                s2.x += wx0 * d2; s2.y += wx1 * d2;
            } else {
                float2 m0 = LD2<BF>(mu, (size_t)j * F3 + fo);
                float2 m1 = LD2<BF>(mu, (size_t)j * F3 + 128 + fo);
                float2 m2 = LD2<BF>(mu, (size_t)j * F3 + 256 + fo);
                s0.x += wx0 * m0.x; s0.y += wx1 * m0.y;
                s1.x += wx0 * m1.x; s1.y += wx1 * m1.y;
                s2.x += wx0 * m2.x; s2.y += wx1 * m2.y;
            }
        }
    }
    ST2<BF>(out, ob + (size_t)a * F3 + fo,       s0);
    ST2<BF>(out, ob + (size_t)a * F3 + 128 + fo, s1);
    ST2<BF>(out, ob + (size_t)a * F3 + 256 + fo, s2);
}

__global__ __launch_bounds__(256) void gather_mu_kernel(
    const void* mu, const void* Wij, const void* dir, const u16* xc,
    const int* idx_j, const int* offsets, const int* perm, void* out,
    int n_atoms, int E, int mode, const int* flag)
{
    if (*flag) {
        if (mode == 1) gmu_body<true, 1>(mu, Wij, dir, xc, idx_j, offsets, perm, out, n_atoms, E);
        else           gmu_body<true, 2>(mu, Wij, dir, xc, idx_j, offsets, perm, out, n_atoms, E);
    } else {
        if (mode == 1) gmu_body<false, 1>(mu, Wij, dir, xc, idx_j, offsets, perm, out, n_atoms, E);
        else           gmu_body<false, 2>(mu, Wij, dir, xc, idx_j, offsets, perm, out, n_atoms, E);
    }
}

// ---------------------------------------------------------------------------
extern "C" void kernel_launch(void* const* d_in, const int* in_sizes, int n_in,
                              void* d_out, int out_size, void* d_ws, size_t ws_size,
                              hipStream_t stream)
{
    const void* q   = d_in[0];
    const void* mu  = d_in[1];
    const void* Wij = d_in[2];
    const void* dir = d_in[3];
    const void* W1  = d_in[4];
    const void* b1  = d_in[5];
    const void* W2  = d_in[6];
    const void* b2  = d_in[7];
    const int* idx_i = (const int*)d_in[8];
    const int* idx_j = (const int*)d_in[9];

    const int n_atoms = in_sizes[0] / F;        // 50000
    const int E       = in_sizes[8];            // 500000

    // ws layout (base ~15.4 MB, known-good):
    //   xc bf16 [A*128] | flag int[4] | counts int[A] | cursor int[A]
    //   | offsets int[A+1] | perm int[E] | [hbuf bf16 [A*128] if ws allows]
    u16* xc      = (u16*)d_ws;
    int* flag    = (int*)(xc + (size_t)n_atoms * F);
    int* counts  = flag + 4;
    int* cursor  = counts + n_atoms;
    int* offsets = cursor + n_atoms;
    int* perm    = offsets + n_atoms + 1;
    u16* hbuf    = (u16*)(perm + E);
    size_t need_h = (size_t)((char*)(hbuf + (size_t)n_atoms * F) - (char*)d_ws);
    const bool useH = (ws_size >= need_h);

    detect_kernel<<<1, 256, 0, stream>>>(q, flag);

    hipMemsetAsync(counts, 0, (size_t)2 * n_atoms * sizeof(int), stream);
    int eBlocks = (E + 255) / 256;
    count_kernel<<<eBlocks, 256, 0, stream>>>(idx_i, counts, E);
    scan_kernel<<<1, 1024, 0, stream>>>(counts, offsets, n_atoms);
    scatter_kernel<<<eBlocks, 256, 0, stream>>>(idx_i, offsets, cursor, perm, E);

    int mlpBlocks = (n_atoms + TA - 1) / TA;
    int gBlocks   = (n_atoms + 3) / 4;

    // pass 0: xq -> out_q
    mlp_kernel<<<mlpBlocks, 256, 0, stream>>>(q, W1, b1, W2, b2, xc, hbuf, 0,
                                              useH ? 1 : 0, n_atoms, flag);
    gather_q_kernel<<<gBlocks, 256, 0, stream>>>(q, Wij, xc, idx_j, offsets, perm,
                                                 d_out, n_atoms, E, flag);
    // pass 1: xR -> out_mu = mu + dmuR*dir
    mlp_kernel<<<mlpBlocks, 256, 0, stream>>>(q, W1, b1, W2, b2, xc, hbuf, 1,
                                              useH ? 2 : 0, n_atoms, flag);
    gather_mu_kernel<<<gBlocks, 256, 0, stream>>>(mu, Wij, dir, xc, idx_j, offsets, perm,
                                                  d_out, n_atoms, E, 1, flag);
    // pass 2: xm -> out_mu += dmumu*mu_j
    mlp_kernel<<<mlpBlocks, 256, 0, stream>>>(q, W1, b1, W2, b2, xc, hbuf, 2,
                                              useH ? 2 : 0, n_atoms, flag);
    gather_mu_kernel<<<gBlocks, 256, 0, stream>>>(mu, Wij, dir, xc, idx_j, offsets, perm,
                                                  d_out, n_atoms, E, 2, flag);
}

// Round 5
// 605.032 us; speedup vs baseline: 1.8613x; 1.1273x over previous
//
#include <hip/hip_runtime.h>

typedef unsigned short u16;
typedef unsigned int   u32;

#define F 128
#define F3 384
#define TA 32          // atoms per MLP block
#define PAD 36         // padded LDS row (floats)

__device__ __forceinline__ float bf2f(u16 v) {
    union { u32 u; float f; } c; c.u = ((u32)v) << 16; return c.f;
}
__device__ __forceinline__ u16 f2bf(float f) {
    union { float fv; u32 u; } c; c.fv = f;
    u32 u = c.u;
    return (u16)((u + 0x7fffu + ((u >> 16) & 1u)) >> 16);   // round-nearest-even
}

// dtype-generic accessors: BF=true -> bf16 (u16) arrays, false -> f32 arrays
template<bool BF> __device__ __forceinline__ float LD(const void* p, size_t i) {
    return BF ? bf2f(((const u16*)p)[i]) : ((const float*)p)[i];
}
template<bool BF> __device__ __forceinline__ void ST(void* p, size_t i, float v) {
    if (BF) ((u16*)p)[i] = f2bf(v); else ((float*)p)[i] = v;
}
template<bool BF> __device__ __forceinline__ float2 LD2(const void* p, size_t i) {
    if (BF) {
        u32 v = *(const u32*)((const u16*)p + i);
        float2 r; r.x = bf2f((u16)(v & 0xffff)); r.y = bf2f((u16)(v >> 16)); return r;
    }
    return *(const float2*)((const float*)p + i);
}
template<bool BF> __device__ __forceinline__ void ST2(void* p, size_t i, float2 v) {
    if (BF) { *(u32*)((u16*)p + i) = ((u32)f2bf(v.y) << 16) | f2bf(v.x); }
    else    { *(float2*)((float*)p + i) = v; }
}
__device__ __forceinline__ float2 LD2bf(const u16* p, size_t i) {
    u32 v = *(const u32*)(p + i);
    float2 r; r.x = bf2f((u16)(v & 0xffff)); r.y = bf2f((u16)(v >> 16)); return r;
}
template<bool BF> __device__ __forceinline__ float4 LD4(const void* p, size_t i) {
    if (BF) {
        uint2 v = *(const uint2*)((const u16*)p + i);
        float4 r;
        r.x = bf2f((u16)(v.x & 0xffff)); r.y = bf2f((u16)(v.x >> 16));
        r.z = bf2f((u16)(v.y & 0xffff)); r.w = bf2f((u16)(v.y >> 16));
        return r;
    }
    return *(const float4*)((const float*)p + i);
}

// ---------------------------------------------------------------------------
// Dtype detector (proven): bf16 arrays have sane exponent fields at even u16
// indices; f32 arrays give ~20% hit-rate there. Evidence says f32, but this
// keeps both modes correct for ~2 µs.
// ---------------------------------------------------------------------------
__global__ __launch_bounds__(256) void detect_kernel(const void* q, int* flag) {
    __shared__ int cnt;
    if (threadIdx.x == 0) cnt = 0;
    __syncthreads();
    const u16* p = (const u16*)q;
    int c = 0;
    for (int i = threadIdx.x; i < 1024; i += 256) {
        u16 v = p[2 * i];
        int e = (v >> 7) & 0xFF;
        if (e >= 100 && e <= 150) c++;
    }
    atomicAdd(&cnt, c);
    __syncthreads();
    if (threadIdx.x == 0) *flag = (cnt > 512) ? 1 : 0;
}

// ---------------------------------------------------------------------------
// mu -> bf16 copy into ws (halves gather bytes; 8 elems/thread)
// ---------------------------------------------------------------------------
template<bool BF>
__device__ void convmu_body(const void* mu, u16* dst, size_t n) {
    size_t i = ((size_t)blockIdx.x * 256 + threadIdx.x) * 8;
    if (i >= n) return;
    if (BF) {
        *(uint4*)(dst + i) = *(const uint4*)((const u16*)mu + i);
    } else {
        float4 a = *(const float4*)((const float*)mu + i);
        float4 b = *(const float4*)((const float*)mu + i + 4);
        uint4 o;
        o.x = ((u32)f2bf(a.y) << 16) | f2bf(a.x);
        o.y = ((u32)f2bf(a.w) << 16) | f2bf(a.z);
        o.z = ((u32)f2bf(b.y) << 16) | f2bf(b.x);
        o.w = ((u32)f2bf(b.w) << 16) | f2bf(b.z);
        *(uint4*)(dst + i) = o;
    }
}
__global__ __launch_bounds__(256) void convmu_kernel(const void* mu, u16* dst,
                                                     size_t n, const int* flag) {
    if (*flag) convmu_body<true >(mu, dst, n);
    else       convmu_body<false>(mu, dst, n);
}

// ---------------------------------------------------------------------------
// Full MLP: h = silu(q@W1+b1) once, then all 3 output chunks -> xcf [A][384] bf16
// ---------------------------------------------------------------------------
template<bool BF>
__device__ void mlpfull_body(const void* q, const void* W1, const void* b1,
                             const void* W2, const void* b2,
                             u16* __restrict__ xcf, int n_atoms)
{
    __shared__ float qT[F][PAD];
    __shared__ float hT[F][PAD];

    const int tid = threadIdx.x;
    const int a0  = blockIdx.x * TA;
    const int c4  = (tid & 31) * 4;
    const int r4  = (tid >> 5) * 4;

    for (int i = tid; i < TA * F / 8; i += 256) {
        int a = i >> 4, f0 = (i & 15) * 8;
        float4 v0, v1;
        if (a0 + a < n_atoms) {
            v0 = LD4<BF>(q, (size_t)(a0 + a) * F + f0);
            v1 = LD4<BF>(q, (size_t)(a0 + a) * F + f0 + 4);
        } else { v0 = v1 = make_float4(0, 0, 0, 0); }
        qT[f0 + 0][a] = v0.x; qT[f0 + 1][a] = v0.y; qT[f0 + 2][a] = v0.z; qT[f0 + 3][a] = v0.w;
        qT[f0 + 4][a] = v1.x; qT[f0 + 5][a] = v1.y; qT[f0 + 6][a] = v1.z; qT[f0 + 7][a] = v1.w;
    }
    __syncthreads();

    // phase 1: h = silu(q@W1 + b1)
    {
        float acc[4][4];
#pragma unroll
        for (int rr = 0; rr < 4; ++rr)
#pragma unroll
            for (int cc = 0; cc < 4; ++cc) acc[rr][cc] = 0.0f;

        for (int f = 0; f < F; ++f) {
            float4 qv = *(const float4*)&qT[f][r4];
            float4 w  = LD4<BF>(W1, (size_t)f * F + c4);
            float qa[4] = {qv.x, qv.y, qv.z, qv.w};
            float wa[4] = {w.x, w.y, w.z, w.w};
#pragma unroll
            for (int rr = 0; rr < 4; ++rr)
#pragma unroll
                for (int cc = 0; cc < 4; ++cc)
                    acc[rr][cc] += qa[rr] * wa[cc];
        }
#pragma unroll
        for (int cc = 0; cc < 4; ++cc) {
            float bb = LD<BF>(b1, c4 + cc);
#pragma unroll
            for (int rr = 0; rr < 4; ++rr) {
                float h = acc[rr][cc] + bb;
                hT[c4 + cc][r4 + rr] = h / (1.0f + __expf(-h));
            }
        }
    }
    __syncthreads();

    // phase 2 x3: all output chunks
    for (int cb = 0; cb < 3; ++cb) {
        float acc[4][4];
#pragma unroll
        for (int rr = 0; rr < 4; ++rr)
#pragma unroll
            for (int cc = 0; cc < 4; ++cc) acc[rr][cc] = 0.0f;

        for (int f = 0; f < F; ++f) {
            float4 hv = *(const float4*)&hT[f][r4];
            float4 w  = LD4<BF>(W2, (size_t)f * F3 + cb * F + c4);
            float ha[4] = {hv.x, hv.y, hv.z, hv.w};
            float wa[4] = {w.x, w.y, w.z, w.w};
#pragma unroll
            for (int rr = 0; rr < 4; ++rr)
#pragma unroll
                for (int cc = 0; cc < 4; ++cc)
                    acc[rr][cc] += ha[rr] * wa[cc];
        }
        float bb[4];
#pragma unroll
        for (int cc = 0; cc < 4; ++cc) bb[cc] = LD<BF>(b2, cb * F + c4 + cc);
#pragma unroll
        for (int rr = 0; rr < 4; ++rr) {
            int ga = a0 + r4 + rr;
            if (ga < n_atoms) {
                uint2 o;
                o.x = ((u32)f2bf(acc[rr][1] + bb[1]) << 16) | f2bf(acc[rr][0] + bb[0]);
                o.y = ((u32)f2bf(acc[rr][3] + bb[3]) << 16) | f2bf(acc[rr][2] + bb[2]);
                *(uint2*)(xcf + (size_t)ga * F3 + cb * F + c4) = o;
            }
        }
    }
}
__global__ __launch_bounds__(256) void mlpfull_kernel(
    const void* q, const void* W1, const void* b1, const void* W2, const void* b2,
    u16* xcf, int n_atoms, const int* flag)
{
    if (*flag) mlpfull_body<true >(q, W1, b1, W2, b2, xcf, n_atoms);
    else       mlpfull_body<false>(q, W1, b1, W2, b2, xcf, n_atoms);
}

// ---------------------------------------------------------------------------
// Chunked MLP (fallback path, proven round-4)
// ---------------------------------------------------------------------------
template<bool BF>
__device__ void mlp_body(const void* q, const void* W1, const void* b1,
                         const void* W2, const void* b2,
                         u16* __restrict__ xc, u16* __restrict__ hbuf,
                         int cb, int mode, int n_atoms)
{
    __shared__ float qT[F][PAD];
    __shared__ float hT[F][PAD];

    const int tid = threadIdx.x;
    const int a0  = blockIdx.x * TA;
    const int c4  = (tid & 31) * 4;
    const int r4  = (tid >> 5) * 4;

    if (mode == 2) {
        for (int i = tid; i < TA * F / 8; i += 256) {
            int a = i >> 4, f0 = (i & 15) * 8;
            float4 v0, v1;
            if (a0 + a < n_atoms) {
                v0 = LD4<true>(hbuf, (size_t)(a0 + a) * F + f0);
                v1 = LD4<true>(hbuf, (size_t)(a0 + a) * F + f0 + 4);
            } else { v0 = v1 = make_float4(0, 0, 0, 0); }
            hT[f0 + 0][a] = v0.x; hT[f0 + 1][a] = v0.y; hT[f0 + 2][a] = v0.z; hT[f0 + 3][a] = v0.w;
            hT[f0 + 4][a] = v1.x; hT[f0 + 5][a] = v1.y; hT[f0 + 6][a] = v1.z; hT[f0 + 7][a] = v1.w;
        }
        __syncthreads();
    } else {
        for (int i = tid; i < TA * F / 8; i += 256) {
            int a = i >> 4, f0 = (i & 15) * 8;
            float4 v0, v1;
            if (a0 + a < n_atoms) {
                v0 = LD4<BF>(q, (size_t)(a0 + a) * F + f0);
                v1 = LD4<BF>(q, (size_t)(a0 + a) * F + f0 + 4);
            } else { v0 = v1 = make_float4(0, 0, 0, 0); }
            qT[f0 + 0][a] = v0.x; qT[f0 + 1][a] = v0.y; qT[f0 + 2][a] = v0.z; qT[f0 + 3][a] = v0.w;
            qT[f0 + 4][a] = v1.x; qT[f0 + 5][a] = v1.y; qT[f0 + 6][a] = v1.z; qT[f0 + 7][a] = v1.w;
        }
        __syncthreads();

        float acc[4][4];
#pragma unroll
        for (int rr = 0; rr < 4; ++rr)
#pragma unroll
            for (int cc = 0; cc < 4; ++cc) acc[rr][cc] = 0.0f;

        for (int f = 0; f < F; ++f) {
            float4 qv = *(const float4*)&qT[f][r4];
            float4 w  = LD4<BF>(W1, (size_t)f * F + c4);
            float qa[4] = {qv.x, qv.y, qv.z, qv.w};
            float wa[4] = {w.x, w.y, w.z, w.w};
#pragma unroll
            for (int rr = 0; rr < 4; ++rr)
#pragma unroll
                for (int cc = 0; cc < 4; ++cc)
                    acc[rr][cc] += qa[rr] * wa[cc];
        }
        float hv[4][4];
#pragma unroll
        for (int cc = 0; cc < 4; ++cc) {
            float bb = LD<BF>(b1, c4 + cc);
#pragma unroll
            for (int rr = 0; rr < 4; ++rr) {
                float h = acc[rr][cc] + bb;
                float s = h / (1.0f + __expf(-h));
                hv[rr][cc] = s;
                hT[c4 + cc][r4 + rr] = s;
            }
        }
        if (mode == 1) {
#pragma unroll
            for (int rr = 0; rr < 4; ++rr) {
                int ga = a0 + r4 + rr;
                if (ga < n_atoms) {
                    *(u32*)(hbuf + (size_t)ga * F + c4)     = ((u32)f2bf(hv[rr][1]) << 16) | f2bf(hv[rr][0]);
                    *(u32*)(hbuf + (size_t)ga * F + c4 + 2) = ((u32)f2bf(hv[rr][3]) << 16) | f2bf(hv[rr][2]);
                }
            }
        }
        __syncthreads();
    }

    float acc[4][4];
#pragma unroll
    for (int rr = 0; rr < 4; ++rr)
#pragma unroll
        for (int cc = 0; cc < 4; ++cc) acc[rr][cc] = 0.0f;

    for (int f = 0; f < F; ++f) {
        float4 hv = *(const float4*)&hT[f][r4];
        float4 w  = LD4<BF>(W2, (size_t)f * F3 + cb * F + c4);
        float ha[4] = {hv.x, hv.y, hv.z, hv.w};
        float wa[4] = {w.x, w.y, w.z, w.w};
#pragma unroll
        for (int rr = 0; rr < 4; ++rr)
#pragma unroll
            for (int cc = 0; cc < 4; ++cc)
                acc[rr][cc] += ha[rr] * wa[cc];
    }
    float bb[4];
#pragma unroll
    for (int cc = 0; cc < 4; ++cc) bb[cc] = LD<BF>(b2, cb * F + c4 + cc);
#pragma unroll
    for (int rr = 0; rr < 4; ++rr) {
        int ga = a0 + r4 + rr;
        if (ga < n_atoms) {
            *(u32*)(xc + (size_t)ga * F + c4)     = ((u32)f2bf(acc[rr][1] + bb[1]) << 16) | f2bf(acc[rr][0] + bb[0]);
            *(u32*)(xc + (size_t)ga * F + c4 + 2) = ((u32)f2bf(acc[rr][3] + bb[3]) << 16) | f2bf(acc[rr][2] + bb[2]);
        }
    }
}
__global__ __launch_bounds__(256) void mlp_kernel(
    const void* q, const void* W1, const void* b1, const void* W2, const void* b2,
    u16* xc, u16* hbuf, int cb, int mode, int n_atoms, const int* flag)
{
    if (*flag) mlp_body<true >(q, W1, b1, W2, b2, xc, hbuf, cb, mode, n_atoms);
    else       mlp_body<false>(q, W1, b1, W2, b2, xc, hbuf, cb, mode, n_atoms);
}

// ---------------------------------------------------------------------------
// CSR build: count -> scan -> scatter perm
// ---------------------------------------------------------------------------
__global__ __launch_bounds__(256) void count_kernel(
    const int* __restrict__ idx_i, int* __restrict__ counts, int E)
{
    int e = blockIdx.x * 256 + threadIdx.x;
    if (e < E) atomicAdd(&counts[idx_i[e]], 1);
}

// single block, 1024 threads, ONE sweep (re-reads counts from L2 for 2nd pass)
__global__ __launch_bounds__(1024) void scan_kernel(
    const int* __restrict__ counts, int* __restrict__ offsets, int n)
{
    __shared__ int buf[1024];
    const int t = threadIdx.x;
    const int m = (n + 1023) >> 10;
    const int i0 = t * m;
    int s = 0;
    for (int r = 0; r < m; ++r) {
        int i = i0 + r;
        if (i < n) s += counts[i];
    }
    buf[t] = s;
    __syncthreads();
    for (int off = 1; off < 1024; off <<= 1) {
        int add = (t >= off) ? buf[t - off] : 0;
        __syncthreads();
        buf[t] += add;
        __syncthreads();
    }
    int run = buf[t] - s;   // exclusive prefix of this thread's chunk
    for (int r = 0; r < m; ++r) {
        int i = i0 + r;
        if (i < n) { offsets[i] = run; run += counts[i]; }
    }
    if (t == 1023) offsets[n] = buf[1023];
}

__global__ __launch_bounds__(256) void scatter_kernel(
    const int* __restrict__ idx_i, const int* __restrict__ offsets,
    int* __restrict__ cursor, int* __restrict__ perm, int E)
{
    int e = blockIdx.x * 256 + threadIdx.x;
    if (e < E) {
        int i = idx_i[e];
        int pos = offsets[i] + atomicAdd(&cursor[i], 1);
        perm[pos] = e;
    }
}

// ---------------------------------------------------------------------------
// FUSED gather: one wave per atom; lane owns features {2l,2l+1} of each chunk.
// out_q[a]  = q[a]  + sum_e Wq*xq[j]
// out_mu[a] = mu[a] + sum_e (WR*xR[j])*dir[e] + (Wm*xm[j])*mu_bf[j]
// ---------------------------------------------------------------------------
template<bool BF>
__device__ void gfused_body(const void* q, const void* mu, const void* Wij,
                            const void* dir, const u16* __restrict__ xcf,
                            const u16* __restrict__ mubf,
                            const int* __restrict__ idx_j,
                            const int* __restrict__ offsets,
                            const int* __restrict__ perm,
                            void* out, int n_atoms, int E)
{
    int a    = blockIdx.x * 4 + (threadIdx.x >> 6);
    int lane = threadIdx.x & 63;
    if (a >= n_atoms) return;
    const size_t fo = 2 * lane;
    const size_t ob = (size_t)n_atoms * F;

    float2 sq = LD2<BF>(q, (size_t)a * F + fo);
    float2 s0 = LD2<BF>(mu, (size_t)a * F3 + fo);
    float2 s1 = LD2<BF>(mu, (size_t)a * F3 + 128 + fo);
    float2 s2 = LD2<BF>(mu, (size_t)a * F3 + 256 + fo);

    int k0 = offsets[a], k1 = offsets[a + 1];
    for (int kb = k0; kb < k1; kb += 64) {
        int cnt = k1 - kb; if (cnt > 64) cnt = 64;
        int e_r = 0, j_r = 0;
        if (lane < cnt) {
            e_r = perm[kb + lane]; if ((unsigned)e_r >= (unsigned)E) e_r = 0;
            j_r = idx_j[e_r];      if ((unsigned)j_r >= (unsigned)n_atoms) j_r = 0;
        }
#pragma unroll 2
        for (int c = 0; c < cnt; ++c) {
            int e = __shfl(e_r, c, 64);
            int j = __shfl(j_r, c, 64);
            const size_t wb = (size_t)e * F3;
            const size_t jb = (size_t)j * F3;
            float2 wq = LD2<BF>(Wij, wb + fo);
            float2 wR = LD2<BF>(Wij, wb + 128 + fo);
            float2 wm = LD2<BF>(Wij, wb + 256 + fo);
            float2 xq = LD2bf(xcf, jb + fo);
            float2 xR = LD2bf(xcf, jb + 128 + fo);
            float2 xm = LD2bf(xcf, jb + 256 + fo);
            float2 m0 = LD2bf(mubf, jb + fo);
            float2 m1 = LD2bf(mubf, jb + 128 + fo);
            float2 m2 = LD2bf(mubf, jb + 256 + fo);
            float d0 = LD<BF>(dir, (size_t)e * 3 + 0);
            float d1 = LD<BF>(dir, (size_t)e * 3 + 1);
            float d2 = LD<BF>(dir, (size_t)e * 3 + 2);

            sq.x += wq.x * xq.x;           sq.y += wq.y * xq.y;
            float tR0 = wR.x * xR.x,  tR1 = wR.y * xR.y;
            float tm0 = wm.x * xm.x,  tm1 = wm.y * xm.y;
            s0.x += tR0 * d0 + tm0 * m0.x; s0.y += tR1 * d0 + tm1 * m0.y;
            s1.x += tR0 * d1 + tm0 * m1.x; s1.y += tR1 * d1 + tm1 * m1.y;
            s2.x += tR0 * d2 + tm0 * m2.x; s2.y += tR1 * d2 + tm1 * m2.y;
        }
    }
    ST2<BF>(out, (size_t)a * F + fo, sq);
    ST2<BF>(out, ob + (size_t)a * F3 + fo,       s0);
    ST2<BF>(out, ob + (size_t)a * F3 + 128 + fo, s1);
    ST2<BF>(out, ob + (size_t)a * F3 + 256 + fo, s2);
}
__global__ __launch_bounds__(256) void gfused_kernel(
    const void* q, const void* mu, const void* Wij, const void* dir,
    const u16* xcf, const u16* mubf, const int* idx_j, const int* offsets,
    const int* perm, void* out, int n_atoms, int E, const int* flag)
{
    if (*flag) gfused_body<true >(q, mu, Wij, dir, xcf, mubf, idx_j, offsets, perm, out, n_atoms, E);
    else       gfused_body<false>(q, mu, Wij, dir, xcf, mubf, idx_j, offsets, perm, out, n_atoms, E);
}

// ---------------------------------------------------------------------------
// Fallback chunked gathers (proven round-4)
// ---------------------------------------------------------------------------
template<bool BF>
__device__ void gq_body(const void* q, const void* Wij, const u16* __restrict__ xc,
                        const int* __restrict__ idx_j, const int* __restrict__ offsets,
                        const int* __restrict__ perm, void* out, int n_atoms, int E)
{
    int a    = blockIdx.x * 4 + (threadIdx.x >> 6);
    int lane = threadIdx.x & 63;
    if (a >= n_atoms) return;
    const size_t fo = 2 * lane;

    float2 s = LD2<BF>(q, (size_t)a * F + fo);
    int k0 = offsets[a], k1 = offsets[a + 1];
    for (int kb = k0; kb < k1; kb += 64) {
        int cnt = k1 - kb; if (cnt > 64) cnt = 64;
        int e_r = 0, j_r = 0;
        if (lane < cnt) {
            e_r = perm[kb + lane]; if ((unsigned)e_r >= (unsigned)E) e_r = 0;
            j_r = idx_j[e_r];      if ((unsigned)j_r >= (unsigned)n_atoms) j_r = 0;
        }
        for (int c = 0; c < cnt; ++c) {
            int e = __shfl(e_r, c, 64);
            int j = __shfl(j_r, c, 64);
            float2 w  = LD2<BF>(Wij, (size_t)e * F3 + fo);
            float2 xv = LD2bf(xc, (size_t)j * F + fo);
            s.x += w.x * xv.x;
            s.y += w.y * xv.y;
        }
    }
    ST2<BF>(out, (size_t)a * F + fo, s);
}
__global__ __launch_bounds__(256) void gather_q_kernel(
    const void* q, const void* Wij, const u16* xc, const int* idx_j,
    const int* offsets, const int* perm, void* out, int n_atoms, int E, const int* flag)
{
    if (*flag) gq_body<true >(q, Wij, xc, idx_j, offsets, perm, out, n_atoms, E);
    else       gq_body<false>(q, Wij, xc, idx_j, offsets, perm, out, n_atoms, E);
}

template<bool BF, int MODE>
__device__ void gmu_body(const void* mu, const void* Wij, const void* dir,
                         const u16* __restrict__ xc, const int* __restrict__ idx_j,
                         const int* __restrict__ offsets, const int* __restrict__ perm,
                         void* out, int n_atoms, int E)
{
    int a    = blockIdx.x * 4 + (threadIdx.x >> 6);
    int lane = threadIdx.x & 63;
    if (a >= n_atoms) return;
    const size_t fo = 2 * lane;
    const size_t ob = (size_t)n_atoms * F;

    float2 s0, s1, s2;
    if (MODE == 1) {
        s0 = LD2<BF>(mu, (size_t)a * F3 + fo);
        s1 = LD2<BF>(mu, (size_t)a * F3 + 128 + fo);
        s2 = LD2<BF>(mu, (size_t)a * F3 + 256 + fo);
    } else {
        s0 = LD2<BF>(out, ob + (size_t)a * F3 + fo);
        s1 = LD2<BF>(out, ob + (size_t)a * F3 + 128 + fo);
        s2 = LD2<BF>(out, ob + (size_t)a * F3 + 256 + fo);
    }

    const int wofs = (MODE == 1) ? 128 : 256;
    int k0 = offsets[a], k1 = offsets[a + 1];
    for (int kb = k0; kb < k1; kb += 64) {
        int cnt = k1 - kb; if (cnt > 64) cnt = 64;
        int e_r = 0, j_r = 0;
        if (lane < cnt) {
            e_r = perm[kb + lane]; if ((unsigned)e_r >= (unsigned)E) e_r = 0;
            j_r = idx_j[e_r];      if ((unsigned)j_r >= (unsigned)n_atoms) j_r = 0;
        }
        for (int c = 0; c < cnt; ++c) {
            int e = __shfl(e_r, c, 64);
            int j = __shfl(j_r, c, 64);
            float2 w  = LD2<BF>(Wij, (size_t)e * F3 + wofs + fo);
            float2 xv = LD2bf(xc, (size_t)j * F + fo);
            float wx0 = w.x * xv.x, wx1 = w.y * xv.y;
            if (MODE == 1) {
                float d0 = LD<BF>(dir, (size_t)e * 3 + 0);
                float d1 = LD<BF>(dir, (size_t)e * 3 + 1);
                float d2 = LD<BF>(dir, (size_t)e * 3 + 2);
                s0.x += wx0 * d0; s0.y += wx1 * d0;
                s1.x += wx0 * d1; s1.y += wx1 * d1;
                s2.x += wx0 * d2; s2.y += wx1 * d2;
            } else {
                float2 m0 = LD2<BF>(mu, (size_t)j * F3 + fo);
                float2 m1 = LD2<BF>(mu, (size_t)j * F3 + 128 + fo);
                float2 m2 = LD2<BF>(mu, (size_t)j * F3 + 256 + fo);
                s0.x += wx0 * m0.x; s0.y += wx1 * m0.y;
                s1.x += wx0 * m1.x; s1.y += wx1 * m1.y;
                s2.x += wx0 * m2.x; s2.y += wx1 * m2.y;
            }
        }
    }
    ST2<BF>(out, ob + (size_t)a * F3 + fo,       s0);
    ST2<BF>(out, ob + (size_t)a * F3 + 128 + fo, s1);
    ST2<BF>(out, ob + (size_t)a * F3 + 256 + fo, s2);
}
__global__ __launch_bounds__(256) void gather_mu_kernel(
    const void* mu, const void* Wij, const void* dir, const u16* xc,
    const int* idx_j, const int* offsets, const int* perm, void* out,
    int n_atoms, int E, int mode, const int* flag)
{
    if (*flag) {
        if (mode == 1) gmu_body<true, 1>(mu, Wij, dir, xc, idx_j, offsets, perm, out, n_atoms, E);
        else           gmu_body<true, 2>(mu, Wij, dir, xc, idx_j, offsets, perm, out, n_atoms, E);
    } else {
        if (mode == 1) gmu_body<false, 1>(mu, Wij, dir, xc, idx_j, offsets, perm, out, n_atoms, E);
        else           gmu_body<false, 2>(mu, Wij, dir, xc, idx_j, offsets, perm, out, n_atoms, E);
    }
}

// ---------------------------------------------------------------------------
extern "C" void kernel_launch(void* const* d_in, const int* in_sizes, int n_in,
                              void* d_out, int out_size, void* d_ws, size_t ws_size,
                              hipStream_t stream)
{
    const void* q   = d_in[0];
    const void* mu  = d_in[1];
    const void* Wij = d_in[2];
    const void* dir = d_in[3];
    const void* W1  = d_in[4];
    const void* b1  = d_in[5];
    const void* W2  = d_in[6];
    const void* b2  = d_in[7];
    const int* idx_i = (const int*)d_in[8];
    const int* idx_j = (const int*)d_in[9];

    const int n_atoms = in_sizes[0] / F;        // 50000
    const int E       = in_sizes[8];            // 500000
    const int eBlocks = (E + 255) / 256;
    const int gBlocks = (n_atoms + 3) / 4;
    const int mlpBlocks = (n_atoms + TA - 1) / TA;

    // FULL layout (~81 MB): xcf bf16[A*384] | mubf bf16[A*384] | flag[4]
    //                       | counts[A] | cursor[A] | offsets[A+1] | perm[E]
    {
        u16* xcf     = (u16*)d_ws;
        u16* mubf    = xcf + (size_t)n_atoms * F3;
        int* flag    = (int*)(mubf + (size_t)n_atoms * F3);
        int* counts  = flag + 4;
        int* cursor  = counts + n_atoms;
        int* offsets = cursor + n_atoms;
        int* perm    = offsets + n_atoms + 1;
        size_t need  = (size_t)((char*)(perm + E) - (char*)d_ws);

        if (ws_size >= need) {
            detect_kernel<<<1, 256, 0, stream>>>(q, flag);
            hipMemsetAsync(counts, 0, (size_t)2 * n_atoms * sizeof(int), stream);
            count_kernel<<<eBlocks, 256, 0, stream>>>(idx_i, counts, E);
            scan_kernel<<<1, 1024, 0, stream>>>(counts, offsets, n_atoms);
            scatter_kernel<<<eBlocks, 256, 0, stream>>>(idx_i, offsets, cursor, perm, E);

            size_t nmu = (size_t)n_atoms * F3;
            convmu_kernel<<<(int)((nmu / 8 + 255) / 256), 256, 0, stream>>>(mu, mubf, nmu, flag);
            mlpfull_kernel<<<mlpBlocks, 256, 0, stream>>>(q, W1, b1, W2, b2, xcf, n_atoms, flag);

            gfused_kernel<<<gBlocks, 256, 0, stream>>>(q, mu, Wij, dir, xcf, mubf,
                                                       idx_j, offsets, perm, d_out,
                                                       n_atoms, E, flag);
            return;
        }
    }

    // FALLBACK (proven round-4 path, ~15.4 MB + optional hbuf)
    u16* xc      = (u16*)d_ws;
    int* flag    = (int*)(xc + (size_t)n_atoms * F);
    int* counts  = flag + 4;
    int* cursor  = counts + n_atoms;
    int* offsets = cursor + n_atoms;
    int* perm    = offsets + n_atoms + 1;
    u16* hbuf    = (u16*)(perm + E);
    size_t need_h = (size_t)((char*)(hbuf + (size_t)n_atoms * F) - (char*)d_ws);
    const bool useH = (ws_size >= need_h);

    detect_kernel<<<1, 256, 0, stream>>>(q, flag);
    hipMemsetAsync(counts, 0, (size_t)2 * n_atoms * sizeof(int), stream);
    count_kernel<<<eBlocks, 256, 0, stream>>>(idx_i, counts, E);
    scan_kernel<<<1, 1024, 0, stream>>>(counts, offsets, n_atoms);
    scatter_kernel<<<eBlocks, 256, 0, stream>>>(idx_i, offsets, cursor, perm, E);

    mlp_kernel<<<mlpBlocks, 256, 0, stream>>>(q, W1, b1, W2, b2, xc, hbuf, 0,
                                              useH ? 1 : 0, n_atoms, flag);
    gather_q_kernel<<<gBlocks, 256, 0, stream>>>(q, Wij, xc, idx_j, offsets, perm,
                                                 d_out, n_atoms, E, flag);
    mlp_kernel<<<mlpBlocks, 256, 0, stream>>>(q, W1, b1, W2, b2, xc, hbuf, 1,
                                              useH ? 2 : 0, n_atoms, flag);
    gather_mu_kernel<<<gBlocks, 256, 0, stream>>>(mu, Wij, dir, xc, idx_j, offsets, perm,
                                                  d_out, n_atoms, E, 1, flag);
    mlp_kernel<<<mlpBlocks, 256, 0, stream>>>(q, W1, b1, W2, b2, xc, hbuf, 2,
                                              useH ? 2 : 0, n_atoms, flag);
    gather_mu_kernel<<<gBlocks, 256, 0, stream>>>(mu, Wij, dir, xc, idx_j, offsets, perm,
                                                  d_out, n_atoms, E, 2, flag);
}